// Round 10
// baseline (67.377 us; speedup 1.0000x reference)
//
#include <hip/hip_runtime.h>

#define K_TINY 1e-12f
#define KEY_EDGE_WEIGHT 0.1f

__device__ __forceinline__ float3 f3(float x, float y, float z) { return make_float3(x, y, z); }
__device__ __forceinline__ float3 add3(float3 a, float3 b) { return f3(a.x + b.x, a.y + b.y, a.z + b.z); }
__device__ __forceinline__ float3 sub3(float3 a, float3 b) { return f3(a.x - b.x, a.y - b.y, a.z - b.z); }
__device__ __forceinline__ float3 scl3(float s, float3 a) { return f3(s * a.x, s * a.y, s * a.z); }
__device__ __forceinline__ float dot3(float3 a, float3 b) { return a.x * b.x + a.y * b.y + a.z * b.z; }
__device__ __forceinline__ float3 cross3(float3 a, float3 b) {
    return f3(a.y * b.z - a.z * b.y,
              a.z * b.x - a.x * b.z,
              a.x * b.y - a.y * b.x);
}

__device__ __forceinline__ float3 qrot(float3 qv, float qw, float3 v) {
    float3 t = add3(cross3(qv, v), scl3(qw, v));
    return add3(v, scl3(2.0f, cross3(qv, t)));
}

__device__ __forceinline__ void qmul(float3 v1, float w1, float3 v2, float w2,
                                     float3* v, float* w) {
    *w = w1 * w2 - dot3(v1, v2);
    *v = add3(add3(scl3(w1, v2), scl3(w2, v1)), cross3(v1, v2));
}

// atan(r) for r in [0,1]; max abs err ~1e-5 (threshold is 0.249 absolute).
__device__ __forceinline__ float atan_poly01(float r) {
    float r2 = r * r;
    float p = fmaf(r2, 0.0208351f, -0.0851330f);
    p = fmaf(r2, p, 0.1801410f);
    p = fmaf(r2, p, -0.3302995f);
    p = fmaf(r2, p, 0.9998660f);
    return r * p;
}

__global__ __launch_bounds__(256) void PoseGraph_kernel(
    const float* __restrict__ nodes,   // [N,7]  t(3), q(4) xyzw
    const float* __restrict__ poses,   // [E,4,4] row-major
    const int*   __restrict__ edges,   // [E,2]  int32
    float*       __restrict__ out,     // [E,6]  tau(3), phi(3)
    int E) {
    const int stride = gridDim.x * blockDim.x;
    for (int e = blockIdx.x * blockDim.x + threadIdx.x; e < E; e += stride) {
        // ---- edge indices (8B aligned int2 load) ----
        int2 ij = *(const int2*)(edges + (size_t)2 * e);

        // ---- node gathers (scalar dword gathers — best measured variant) ----
        const float* pa = nodes + (size_t)7 * ij.x;
        const float* pb = nodes + (size_t)7 * ij.y;
        float3 t1  = f3(pa[0], pa[1], pa[2]);
        float3 q1v = f3(pa[3], pa[4], pa[5]);
        float  q1w = pa[6];
        float3 t2  = f3(pb[0], pb[1], pb[2]);
        float3 q2v = f3(pb[3], pb[4], pb[5]);
        float  q2w = pb[6];

        // ---- pose rows (16B aligned, coalesced) ----
        const float4* p4 = (const float4*)(poses + (size_t)e * 16);
        float4 r0 = p4[0];
        float4 r1 = p4[1];
        float4 r2 = p4[2];

        // ---- relative node transform: q1i = conj(q1) ----
        float3 q1iv = f3(-q1v.x, -q1v.y, -q1v.z);
        float3 t12 = qrot(q1iv, q1w, sub3(t2, t1));
        float3 q12v; float q12w;
        qmul(q1iv, q1w, q2v, q2w, &q12v, &q12w);

        // ---- pose matrix -> (tp, qp), branchless copysign mat2SE3 ----
        float m00 = r0.x, m01 = r0.y, m02 = r0.z;
        float m10 = r1.x, m11 = r1.y, m12 = r1.z;
        float m20 = r2.x, m21 = r2.y, m22 = r2.z;
        float3 tp = f3(r0.w, r1.w, r2.w);

        float qpw = 0.5f * sqrtf(fmaxf(1.0f + m00 + m11 + m22, K_TINY));
        float qpx = ((m21 - m12 >= 0.0f) ? 0.5f : -0.5f) * sqrtf(fmaxf(1.0f + m00 - m11 - m22, K_TINY));
        float qpy = ((m02 - m20 >= 0.0f) ? 0.5f : -0.5f) * sqrtf(fmaxf(1.0f - m00 + m11 - m22, K_TINY));
        float qpz = ((m10 - m01 >= 0.0f) ? 0.5f : -0.5f) * sqrtf(fmaxf(1.0f - m00 - m11 + m22, K_TINY));
        float3 qpv = f3(qpx, qpy, qpz);

        // ---- compose error transform ----
        float3 te = add3(tp, qrot(qpv, qpw, t12));
        float3 qev; float qew;
        qmul(qpv, qpw, q12v, q12w, &qev, &qew);

        // ---- SO3 log, branchless fast path ----
        // After sign flip w >= 0, so atan2(n,w) in [0,pi/2]:
        //   n<=w: atan(n/w);  n>w: pi/2 - atan(w/n).
        // As n->0 this smoothly matches the reference's series branch
        // (2/w - 2n^2/(3w^3)) within ~2e-4 — far inside the 0.249 threshold.
        float s = (qew < 0.0f) ? -1.0f : 1.0f;
        float3 v = scl3(s, qev);
        float w = s * qew;                       // >= 0
        float nn2 = dot3(v, v);
        float n = sqrtf(fmaxf(nn2, K_TINY));
        float mn = fminf(n, w), mx = fmaxf(n, w);
        float r = mn * __builtin_amdgcn_rcpf(mx);
        float at = atan_poly01(r);
        float ang = (n > w) ? (1.5707963f - at) : at;   // atan2(n, w)
        float scale = 2.0f * ang * __builtin_amdgcn_rcpf(n);
        float3 phi = scl3(scale, v);

        // ---- SE3 log tail: V^{-1} * t, branchless series for coef ----
        // coef = (1 - (th/2)cot(th/2))/th^2
        //      = 1/12 + u/720 + u^2/30240 + u^3/1209600 + u^4/47900160,  u = th^2.
        // Valid for th in [0,pi] (err <= ~6e-5); reference's small branch is the
        // 2-term truncation of the same series.
        float u = dot3(phi, phi);
        float coef = fmaf(u, 2.0876757e-8f, 8.2671958e-7f);
        coef = fmaf(u, coef, 3.3068783e-5f);
        coef = fmaf(u, coef, 1.3888889e-3f);
        coef = fmaf(u, coef, 8.3333333e-2f);
        float3 pxt = cross3(phi, te);
        float3 tau = add3(sub3(te, scl3(0.5f, pxt)), scl3(coef, cross3(phi, pxt)));

        // ---- weight (last edge is the key edge) ----
        float wgt = (e == E - 1) ? KEY_EDGE_WEIGHT : 1.0f;

        // ---- store 24B as 3x float2 (8B aligned) ----
        float* o = out + (size_t)6 * e;
        *(float2*)(o + 0) = make_float2(tau.x * wgt, tau.y * wgt);
        *(float2*)(o + 2) = make_float2(tau.z * wgt, phi.x * wgt);
        *(float2*)(o + 4) = make_float2(phi.y * wgt, phi.z * wgt);
    }
}

extern "C" void kernel_launch(void* const* d_in, const int* in_sizes, int n_in,
                              void* d_out, int out_size, void* d_ws, size_t ws_size,
                              hipStream_t stream) {
    const float* nodes = (const float*)d_in[0];   // [N,7]
    const float* poses = (const float*)d_in[1];   // [E,4,4]
    const int*   edges = (const int*)d_in[2];     // [E,2] int32
    float* out = (float*)d_out;

    int E = in_sizes[2] / 2;
    int threads = 256;
    // Persistent plain grid-stride: 8 blocks/CU x 256 CUs; each thread walks
    // ~4 edges, amortizing its gather-latency prologue without pipeline VGPRs.
    int blocks = 2048;
    int max_blocks = (E + threads - 1) / threads;
    if (blocks > max_blocks) blocks = max_blocks;
    PoseGraph_kernel<<<blocks, threads, 0, stream>>>(nodes, poses, edges, out, E);
}

// Round 11
// 52.875 us; speedup vs baseline: 1.2743x; 1.2743x over previous
//
#include <hip/hip_runtime.h>

#define K_TINY 1e-12f
#define KEY_EDGE_WEIGHT 0.1f

__device__ __forceinline__ float3 f3(float x, float y, float z) { return make_float3(x, y, z); }
__device__ __forceinline__ float3 add3(float3 a, float3 b) { return f3(a.x + b.x, a.y + b.y, a.z + b.z); }
__device__ __forceinline__ float3 sub3(float3 a, float3 b) { return f3(a.x - b.x, a.y - b.y, a.z - b.z); }
__device__ __forceinline__ float3 scl3(float s, float3 a) { return f3(s * a.x, s * a.y, s * a.z); }
__device__ __forceinline__ float dot3(float3 a, float3 b) { return a.x * b.x + a.y * b.y + a.z * b.z; }
__device__ __forceinline__ float3 cross3(float3 a, float3 b) {
    return f3(a.y * b.z - a.z * b.y,
              a.z * b.x - a.x * b.z,
              a.x * b.y - a.y * b.x);
}

__device__ __forceinline__ float3 qrot(float3 qv, float qw, float3 v) {
    float3 t = add3(cross3(qv, v), scl3(qw, v));
    return add3(v, scl3(2.0f, cross3(qv, t)));
}

__device__ __forceinline__ void qmul(float3 v1, float w1, float3 v2, float w2,
                                     float3* v, float* w) {
    *w = w1 * w2 - dot3(v1, v2);
    *v = add3(add3(scl3(w1, v2), scl3(w2, v1)), cross3(v1, v2));
}

// atan(r) for r in [0,1]; max abs err ~1e-5 (output threshold is 0.249 abs).
__device__ __forceinline__ float atan_poly01(float r) {
    float r2 = r * r;
    float p = fmaf(r2, 0.0208351f, -0.0851330f);
    p = fmaf(r2, p, 0.1801410f);
    p = fmaf(r2, p, -0.3302995f);
    p = fmaf(r2, p, 0.9998660f);
    return r * p;
}

// R4 structure (best measured: 1 edge/thread, consecutive-block dispatch,
// scalar dword gathers) + branchless fast math (R10-validated, absmax 0.0625).
__global__ __launch_bounds__(256) void PoseGraph_kernel(
    const float* __restrict__ nodes,   // [N,7]  t(3), q(4) xyzw
    const float* __restrict__ poses,   // [E,4,4] row-major
    const int*   __restrict__ edges,   // [E,2]  int32
    float*       __restrict__ out,     // [E,6]  tau(3), phi(3)
    int E) {
    int e = blockIdx.x * blockDim.x + threadIdx.x;
    if (e >= E) return;

    // ---- edge indices (8B aligned int2 load) ----
    int2 ij = *(const int2*)(edges + (size_t)2 * e);

    // ---- node gathers (scalar dword gathers — best measured variant) ----
    const float* pa = nodes + (size_t)7 * ij.x;
    const float* pb = nodes + (size_t)7 * ij.y;
    float3 t1  = f3(pa[0], pa[1], pa[2]);
    float3 q1v = f3(pa[3], pa[4], pa[5]);
    float  q1w = pa[6];
    float3 t2  = f3(pb[0], pb[1], pb[2]);
    float3 q2v = f3(pb[3], pb[4], pb[5]);
    float  q2w = pb[6];

    // ---- pose rows (16B aligned, coalesced) ----
    const float4* p4 = (const float4*)(poses + (size_t)e * 16);
    float4 r0 = p4[0];
    float4 r1 = p4[1];
    float4 r2 = p4[2];

    // ---- relative node transform: q1i = conj(q1) ----
    float3 q1iv = f3(-q1v.x, -q1v.y, -q1v.z);
    float3 t12 = qrot(q1iv, q1w, sub3(t2, t1));
    float3 q12v; float q12w;
    qmul(q1iv, q1w, q2v, q2w, &q12v, &q12w);

    // ---- pose matrix -> (tp, qp), branchless copysign mat2SE3 ----
    float m00 = r0.x, m01 = r0.y, m02 = r0.z;
    float m10 = r1.x, m11 = r1.y, m12 = r1.z;
    float m20 = r2.x, m21 = r2.y, m22 = r2.z;
    float3 tp = f3(r0.w, r1.w, r2.w);

    float qpw = 0.5f * sqrtf(fmaxf(1.0f + m00 + m11 + m22, K_TINY));
    float qpx = ((m21 - m12 >= 0.0f) ? 0.5f : -0.5f) * sqrtf(fmaxf(1.0f + m00 - m11 - m22, K_TINY));
    float qpy = ((m02 - m20 >= 0.0f) ? 0.5f : -0.5f) * sqrtf(fmaxf(1.0f - m00 + m11 - m22, K_TINY));
    float qpz = ((m10 - m01 >= 0.0f) ? 0.5f : -0.5f) * sqrtf(fmaxf(1.0f - m00 - m11 + m22, K_TINY));
    float3 qpv = f3(qpx, qpy, qpz);

    // ---- compose error transform ----
    float3 te = add3(tp, qrot(qpv, qpw, t12));
    float3 qev; float qew;
    qmul(qpv, qpw, q12v, q12w, &qev, &qew);

    // ---- SO3 log, branchless fast path ----
    // After sign flip w >= 0, so atan2(n,w) in [0,pi/2]:
    //   n<=w: atan(n/w);  n>w: pi/2 - atan(w/n).
    // Smoothly matches the reference's small-n series branch within ~2e-4.
    float s = (qew < 0.0f) ? -1.0f : 1.0f;
    float3 v = scl3(s, qev);
    float w = s * qew;                       // >= 0
    float nn2 = dot3(v, v);
    float n = sqrtf(fmaxf(nn2, K_TINY));
    float mn = fminf(n, w), mx = fmaxf(n, w);
    float r = mn * __builtin_amdgcn_rcpf(mx);
    float at = atan_poly01(r);
    float ang = (n > w) ? (1.5707963f - at) : at;   // atan2(n, w)
    float scale = 2.0f * ang * __builtin_amdgcn_rcpf(n);
    float3 phi = scl3(scale, v);

    // ---- SE3 log tail: V^{-1} * t, branchless series for coef ----
    // coef = (1 - (th/2)cot(th/2))/th^2
    //      = 1/12 + u/720 + u^2/30240 + u^3/1209600 + u^4/47900160,  u = th^2.
    // Valid on th in [0,pi] (err <= ~7e-5); the reference's small branch is
    // the 2-term truncation of this same series.
    float u = dot3(phi, phi);
    float coef = fmaf(u, 2.0876757e-8f, 8.2671958e-7f);
    coef = fmaf(u, coef, 3.3068783e-5f);
    coef = fmaf(u, coef, 1.3888889e-3f);
    coef = fmaf(u, coef, 8.3333333e-2f);
    float3 pxt = cross3(phi, te);
    float3 tau = add3(sub3(te, scl3(0.5f, pxt)), scl3(coef, cross3(phi, pxt)));

    // ---- weight (last edge is the key edge) ----
    float wgt = (e == E - 1) ? KEY_EDGE_WEIGHT : 1.0f;

    // ---- store 24B as 3x float2 (8B aligned) ----
    float* o = out + (size_t)6 * e;
    *(float2*)(o + 0) = make_float2(tau.x * wgt, tau.y * wgt);
    *(float2*)(o + 2) = make_float2(tau.z * wgt, phi.x * wgt);
    *(float2*)(o + 4) = make_float2(phi.y * wgt, phi.z * wgt);
}

extern "C" void kernel_launch(void* const* d_in, const int* in_sizes, int n_in,
                              void* d_out, int out_size, void* d_ws, size_t ws_size,
                              hipStream_t stream) {
    const float* nodes = (const float*)d_in[0];   // [N,7]
    const float* poses = (const float*)d_in[1];   // [E,4,4]
    const int*   edges = (const int*)d_in[2];     // [E,2] int32
    float* out = (float*)d_out;

    int E = in_sizes[2] / 2;
    int threads = 256;
    int blocks = (E + threads - 1) / threads;     // R4 dispatch: best measured
    PoseGraph_kernel<<<blocks, threads, 0, stream>>>(nodes, poses, edges, out, E);
}